// Round 10
// baseline (148.981 us; speedup 1.0000x reference)
//
#include <hip/hip_runtime.h>

typedef __attribute__((ext_vector_type(8))) short short8;
typedef __attribute__((ext_vector_type(4))) float f32x4;

constexpr int NTOK = 65536;
constexpr int DIM  = 128;
constexpr int NK   = 1024;

__device__ __forceinline__ unsigned short f2bf(float f) {
  unsigned int u = __float_as_uint(f);
  unsigned int r = u + 0x7fffu + ((u >> 16) & 1u);
  return (unsigned short)(r >> 16);
}
__device__ __forceinline__ float bf2f(unsigned short h) {
  return __uint_as_float(((unsigned int)h) << 16);
}
__device__ __forceinline__ void gload_lds16(const void* g, void* l) {
  __builtin_amdgcn_global_load_lds(
      (const __attribute__((address_space(1))) unsigned int*)g,
      (__attribute__((address_space(3))) unsigned int*)l, 16, 0, 0);
}

// ---- prep: emb -> pre-swizzled bf16 hi|lo image (contiguous 8KB per 16 codes)
//      + embT + f64 |e|^2 + scaled-key e2s; zeroes nflag ----
__global__ void bprep_k(const float* __restrict__ emb, char* __restrict__ bp,
                        float* __restrict__ embT, float* __restrict__ e2s,
                        double* __restrict__ en2d, int* __restrict__ nflag) {
  int i = blockIdx.x * 256 + threadIdx.x;   // 0..16383
  if (i == 0) *nflag = 0;
  int c = i >> 4;          // code
  int g = i & 15;          // dim group (8 dims)
  float4 v0 = *(const float4*)&emb[c * 128 + g * 8];
  float4 v1 = *(const float4*)&emb[c * 128 + g * 8 + 4];
  float vf[8] = {v0.x, v0.y, v0.z, v0.w, v1.x, v1.y, v1.z, v1.w};
  unsigned short hh[8], ll[8];
  double pacc = 0.0;
#pragma unroll
  for (int j = 0; j < 8; j++) {
    hh[j] = f2bf(vf[j]);
    ll[j] = f2bf(vf[j] - bf2f(hh[j]));
    embT[(g * 8 + j) * NK + c] = vf[j];
    pacc = fma((double)vf[j], (double)vf[j], pacc);
  }
  uint4 hv, lv;
  hv.x = (unsigned)hh[0] | ((unsigned)hh[1] << 16); hv.y = (unsigned)hh[2] | ((unsigned)hh[3] << 16);
  hv.z = (unsigned)hh[4] | ((unsigned)hh[5] << 16); hv.w = (unsigned)hh[6] | ((unsigned)hh[7] << 16);
  lv.x = (unsigned)ll[0] | ((unsigned)ll[1] << 16); lv.y = (unsigned)ll[2] | ((unsigned)ll[3] << 16);
  lv.z = (unsigned)ll[4] | ((unsigned)ll[5] << 16); lv.w = (unsigned)ll[6] | ((unsigned)ll[7] << 16);
  int c16 = c >> 4, j16 = c & 15;
  int sw = (j16 & 7) << 4;
  char* base = bp + c16 * 8192 + j16 * 512;
  *(uint4*)(base + ((g * 16) ^ sw)) = hv;
  *(uint4*)(base + 256 + ((g * 16) ^ sw)) = lv;
#pragma unroll
  for (int mask = 1; mask < 16; mask <<= 1) pacc += __shfl_xor(pacc, mask);
  if (g == 0) {
    en2d[c] = pacc;
    e2s[c] = (float)(pacc * 134217728.0 + 1073741824.0);  // e2*2^27 + 2^30
  }
}

// ---- main: MFMA bf16-split distance + u32-key argmin ----
// 1024 blocks x 128 thr (2 waves), 4 blocks/CU. BM=64, wave tile 32 rows (m=2)
// x 16 cols. 64 chunks of 16 codes; 3-deep counted-vmcnt pipeline, 3x8KB bufs.
__global__ __launch_bounds__(128, 2)
void argmin_k(const float* __restrict__ x, const char* __restrict__ bp,
              const float* __restrict__ e2s, int* __restrict__ idx_arr,
              float* __restrict__ out_idx, int* __restrict__ nflag,
              int* __restrict__ flags) {
  __shared__ __align__(16) char smem[24576];
  __shared__ __align__(16) float se2[1024];
  const int t    = threadIdx.x;
  const int lane = t & 63;
  const int w    = t >> 6;              // 0..1
  const int l15  = lane & 15;
  const int lo4  = lane >> 4;
  const int rbase = blockIdx.x * 64;
  const int sw   = (l15 & 7) << 4;

  // stage e2s -> LDS (2 gload_lds per wave, 4KB total)
  {
    const char* gsrc = (const char*)e2s + w * 2048 + lane * 16;
    char* ldst = (char*)se2 + w * 2048;
    gload_lds16(gsrc, ldst);
    gload_lds16(gsrc + 1024, ldst + 1024);
  }

  // A-frags (m=2): global -> regs with in-reg bf16 hi/lo split
  short8 ah[2][4], al[2][4];
#pragma unroll
  for (int m = 0; m < 2; m++)
#pragma unroll
    for (int kk = 0; kk < 4; kk++) {
      const float* xp = &x[(rbase + w * 32 + m * 16 + l15) * 128 + kk * 32 + lo4 * 8];
      float4 v0 = *(const float4*)xp;
      float4 v1 = *(const float4*)(xp + 4);
      float vf[8] = {v0.x, v0.y, v0.z, v0.w, v1.x, v1.y, v1.z, v1.w};
      unsigned short hh[8], ll[8];
#pragma unroll
      for (int j = 0; j < 8; j++) {
        hh[j] = f2bf(vf[j]);
        ll[j] = f2bf(vf[j] - bf2f(hh[j]));
      }
      unsigned hu[4] = {(unsigned)hh[0] | ((unsigned)hh[1] << 16), (unsigned)hh[2] | ((unsigned)hh[3] << 16),
                        (unsigned)hh[4] | ((unsigned)hh[5] << 16), (unsigned)hh[6] | ((unsigned)hh[7] << 16)};
      unsigned lu[4] = {(unsigned)ll[0] | ((unsigned)ll[1] << 16), (unsigned)ll[2] | ((unsigned)ll[3] << 16),
                        (unsigned)ll[4] | ((unsigned)ll[5] << 16), (unsigned)ll[6] | ((unsigned)ll[7] << 16)};
      ah[m][kk] = *(short8*)hu;
      al[m][kk] = *(short8*)lu;
    }

  unsigned bv[2][4], b2[2][4];
#pragma unroll
  for (int m = 0; m < 2; m++)
#pragma unroll
    for (int r = 0; r < 4; r++) { bv[m][r] = 0xFFFFFFFFu; b2[m][r] = 0xFFFFFFFFu; }

  // precomputed swizzled LDS offsets
  int offH[4], offL[4];
#pragma unroll
  for (int kk = 0; kk < 4; kk++) {
    int byte_ = l15 * 512 + kk * 64 + (lo4 << 4);
    offH[kk] = byte_ ^ sw;
    offL[kk] = (byte_ + 256) ^ sw;
  }

  __syncthreads();   // full drain: se2 resident, A-loads complete, vmcnt=0

  // stage chunks 0 and 1 (4 gload_lds each per wave)
#pragma unroll
  for (int c = 0; c < 2; c++) {
    const char* gsrc = bp + c * 8192 + w * 4096 + lane * 16;
    char* ldst = smem + c * 8192 + w * 4096;
#pragma unroll
    for (int u = 0; u < 4; u++) gload_lds16(gsrc + u * 1024, ldst + u * 1024);
  }
  asm volatile("s_waitcnt vmcnt(4)" ::: "memory");   // my chunk-0 loads landed
  __builtin_amdgcn_s_barrier();                      // everyone's chunk 0 landed

  int bufb = 0, sb = 16384;
  for (int c = 0; c < 64; c++) {
    // stage c+2 into sb (overwrites c-1's buffer; safe past last barrier)
    if (c < 62) {
      const char* gsrc = bp + (c + 2) * 8192 + w * 4096 + lane * 16;
      char* ldst = smem + sb + w * 4096;
#pragma unroll
      for (int u = 0; u < 4; u++) gload_lds16(gsrc + u * 1024, ldst + u * 1024);
    }
    asm volatile("" ::: "memory");   // keep stage issue above compute

    float e2v = se2[c * 16 + l15];

    f32x4 acc0 = (f32x4)(0.0f);
    f32x4 acc1 = (f32x4)(0.0f);

    __builtin_amdgcn_s_setprio(1);
#pragma unroll
    for (int kk = 0; kk < 4; kk++) {
      short8 bhv = *(short8*)&smem[bufb + offH[kk]];
      short8 blv = *(short8*)&smem[bufb + offL[kk]];
      acc0 = __builtin_amdgcn_mfma_f32_16x16x32_bf16(ah[0][kk], bhv, acc0, 0, 0, 0);
      acc1 = __builtin_amdgcn_mfma_f32_16x16x32_bf16(ah[1][kk], bhv, acc1, 0, 0, 0);
      acc0 = __builtin_amdgcn_mfma_f32_16x16x32_bf16(ah[0][kk], blv, acc0, 0, 0, 0);
      acc1 = __builtin_amdgcn_mfma_f32_16x16x32_bf16(ah[1][kk], blv, acc1, 0, 0, 0);
      acc0 = __builtin_amdgcn_mfma_f32_16x16x32_bf16(al[0][kk], bhv, acc0, 0, 0, 0);
      acc1 = __builtin_amdgcn_mfma_f32_16x16x32_bf16(al[1][kk], bhv, acc1, 0, 0, 0);
    }
    __builtin_amdgcn_s_setprio(0);

    // u32-key epilogue: key = (u32(e2s - 2^28*dot) & ~1023) | col
    unsigned col = (unsigned)(c * 16 + l15);
#pragma unroll
    for (int r = 0; r < 4; r++) {
      {
        float ks = fmaf(acc0[r], -268435456.0f, e2v);
        unsigned key = ((unsigned)ks & 0xFFFFFC00u) | col;
        unsigned old = bv[0][r];
        bv[0][r] = min(old, key);
        b2[0][r] = min(b2[0][r], max(old, key));
      }
      {
        float ks = fmaf(acc1[r], -268435456.0f, e2v);
        unsigned key = ((unsigned)ks & 0xFFFFFC00u) | col;
        unsigned old = bv[1][r];
        bv[1][r] = min(old, key);
        b2[1][r] = min(b2[1][r], max(old, key));
      }
    }

    // counted wait: c+1 landed (mine), then rendezvous — c+2 stays in flight
    if (c < 63) {
      if (c < 61) { asm volatile("s_waitcnt vmcnt(4)" ::: "memory"); }
      else        { asm volatile("s_waitcnt vmcnt(0)" ::: "memory"); }
      __builtin_amdgcn_s_barrier();
    }
    bufb += 8192; if (bufb == 24576) bufb = 0;
    sb   += 8192; if (sb   == 24576) sb   = 0;
  }

  // reduce over the 16 column-lanes (u32 min keeps tie-break = smaller col)
#pragma unroll
  for (int m = 0; m < 2; m++)
#pragma unroll
    for (int r = 0; r < 4; r++) {
      unsigned v = bv[m][r], v2 = b2[m][r];
      for (int mask = 1; mask < 16; mask <<= 1) {
        unsigned ov = __shfl_xor(v, mask);
        unsigned o2 = __shfl_xor(v2, mask);
        v2 = min(min(v2, o2), max(v, ov));
        v  = min(v, ov);
      }
      if (l15 == 0) {
        int row = rbase + w * 32 + m * 16 + lo4 * 4 + r;
        int ii = (int)(v & 1023u);
        idx_arr[row] = ii;
        out_idx[row] = (float)ii;
        if ((v2 >> 10) - (v >> 10) < 39u) {   // gap < 3e-4 in score units
          int p = atomicAdd(nflag, 1); flags[p] = row;
        }
      }
    }
}

// ---- exact f64 recompute for near-tie rows (coalesced via embT) ----
__global__ __launch_bounds__(256)
void fb_k(const float* __restrict__ x, const float* __restrict__ embT,
          const double* __restrict__ en2d, const int* __restrict__ nflag,
          const int* __restrict__ flags, int* __restrict__ idx_arr,
          float* __restrict__ out_idx) {
  int n = *nflag;
  __shared__ double xsh[DIM];
  __shared__ double sv[256];
  __shared__ int    si[256];
  int t = threadIdx.x;
  for (int f = blockIdx.x; f < n; f += gridDim.x) {
    int row = flags[f];
    __syncthreads();
    if (t < DIM) xsh[t] = (double)x[row * DIM + t];
    __syncthreads();
    double xe0 = 0.0, xe1 = 0.0, xe2 = 0.0, xe3 = 0.0;
#pragma unroll 4
    for (int d = 0; d < DIM; d++) {
      float4 v = *(const float4*)&embT[d * NK + t * 4];
      double xd = xsh[d];
      xe0 = fma((double)v.x, xd, xe0);
      xe1 = fma((double)v.y, xd, xe1);
      xe2 = fma((double)v.z, xd, xe2);
      xe3 = fma((double)v.w, xd, xe3);
    }
    double s0 = en2d[t * 4 + 0] - 2.0 * xe0;
    double s1 = en2d[t * 4 + 1] - 2.0 * xe1;
    double s2 = en2d[t * 4 + 2] - 2.0 * xe2;
    double s3 = en2d[t * 4 + 3] - 2.0 * xe3;
    double bvv = s0; int bii = t * 4;
    if (s1 < bvv) { bvv = s1; bii = t * 4 + 1; }
    if (s2 < bvv) { bvv = s2; bii = t * 4 + 2; }
    if (s3 < bvv) { bvv = s3; bii = t * 4 + 3; }
    sv[t] = bvv; si[t] = bii;
    __syncthreads();
    for (int sh = 128; sh > 0; sh >>= 1) {
      if (t < sh) {
        double ov = sv[t + sh]; int oi = si[t + sh];
        if (ov < sv[t] || (ov == sv[t] && oi < si[t])) { sv[t] = ov; si[t] = oi; }
      }
      __syncthreads();
    }
    if (t == 0) { idx_arr[row] = si[0]; out_idx[row] = (float)si[0]; }
  }
}

// ---- per-block histogram (LDS bins, plain stores) ----
__global__ void histb_k(const int* __restrict__ idx, unsigned* __restrict__ bcount) {
  __shared__ unsigned bins[NK];
  int t = threadIdx.x;
  for (int b = t; b < NK; b += 256) bins[b] = 0u;
  __syncthreads();
#pragma unroll
  for (int j = 0; j < 4; j++)
    atomicAdd(&bins[idx[blockIdx.x * 1024 + j * 256 + t]], 1u);
  __syncthreads();
  for (int b = t; b < NK; b += 256) bcount[blockIdx.x * NK + b] = bins[b];
}

// ---- totals + scan + per-block starts + ncs/csk (fin folded in) ----
__global__ void scan_k(unsigned* __restrict__ bcount, unsigned* __restrict__ icounts,
                       unsigned* __restrict__ offsets, const float* __restrict__ cs,
                       float* __restrict__ out_ncs, float* __restrict__ csk) {
  __shared__ unsigned sc[NK];
  __shared__ float sf[NK];
  int t = threadIdx.x;
  unsigned tot = 0;
#pragma unroll 8
  for (int b = 0; b < 64; b++) tot += bcount[b * NK + t];
  icounts[t] = tot;
  sc[t] = tot;
  __syncthreads();
  for (int off = 1; off < NK; off <<= 1) {
    unsigned v = (t >= off) ? sc[t - off] : 0u;
    __syncthreads();
    sc[t] += v;
    __syncthreads();
  }
  unsigned excl = sc[t] - tot;
  offsets[t] = excl;
  unsigned run = excl;
#pragma unroll 8
  for (int b = 0; b < 64; b++) {
    unsigned c = bcount[b * NK + t];
    bcount[b * NK + t] = run;          // becomes per-block start
    run += c;
  }
  // EMA cluster size + csk
  float c0 = cs[t];
  float ncs = c0 * 0.99f + 0.01f * (float)tot;
  out_ncs[t] = ncs;
  sf[t] = c0;
  __syncthreads();
  for (int s = 512; s > 0; s >>= 1) {
    if (t < s) sf[t] += sf[t + s];
    __syncthreads();
  }
  float n = 0.99f * sf[0] + 655.36f;   // sum(ncs) = 0.99*sum(cs) + 0.01*65536
  csk[t] = (ncs + 1e-5f) / (n + 1024.0f * 1e-5f) * n;
}

// ---- scatter row ids (LDS cursors; no global atomics) ----
__global__ void scatter_k(const int* __restrict__ idx, const unsigned* __restrict__ bstart,
                          int* __restrict__ order) {
  __shared__ unsigned cur[NK];
  int t = threadIdx.x;
  for (int b = t; b < NK; b += 256) cur[b] = bstart[blockIdx.x * NK + b];
  __syncthreads();
#pragma unroll
  for (int j = 0; j < 4; j++) {
    int r = blockIdx.x * 1024 + j * 256 + t;
    unsigned p = atomicAdd(&cur[idx[r]], 1u);
    order[p] = r;
  }
}

// ---- fused gather: out_q, loss partials, dw_embed sums (no atomics) ----
__global__ __launch_bounds__(512)
void fgather_k(const float* __restrict__ x, const float* __restrict__ emb,
               const unsigned* __restrict__ offsets, const unsigned* __restrict__ icounts,
               const int* __restrict__ order, float* __restrict__ out_q,
               float* __restrict__ dwsum, float* __restrict__ partial) {
  int k = blockIdx.x, t = threadIdx.x;
  int d = t & 127, h = t >> 7;   // h = 0..3
  float e = emb[k * DIM + d];
  unsigned s = offsets[k], cnt = icounts[k];
  float acc = 0.f, ls = 0.f;
  for (unsigned j = h; j < cnt; j += 4) {
    int row = order[s + j];
    float xv = x[row * DIM + d];
    out_q[row * DIM + d] = e;
    acc += xv;
    float dd = e - xv;
    ls += dd * dd;
  }
  __shared__ float sa[512], sl[512];
  sa[t] = acc; sl[t] = ls;
  __syncthreads();
  if (t < 128) dwsum[k * DIM + t] = sa[t] + sa[t + 128] + sa[t + 256] + sa[t + 384];
  for (int sh = 256; sh > 0; sh >>= 1) {
    if (t < sh) sl[t] += sl[t + sh];
    __syncthreads();
  }
  if (t == 0) partial[k] = sl[0];
}

// ---- embed_avg EMA + new embedding; block 0 reduces loss ----
__global__ void emb_k(const float* __restrict__ embed_avg, const float* __restrict__ dwsum,
                      const float* __restrict__ csk, const float* __restrict__ partial,
                      float* __restrict__ out_nemb, float* __restrict__ out_nea,
                      float* __restrict__ out_loss) {
  if (blockIdx.x == 0) {
    __shared__ float red[256];
    int t = threadIdx.x;
    red[t] = partial[t] + partial[t + 256] + partial[t + 512] + partial[t + 768];
    __syncthreads();
    for (int sh = 128; sh > 0; sh >>= 1) {
      if (t < sh) red[t] += red[t + sh];
      __syncthreads();
    }
    if (t == 0) out_loss[0] = 2.0f * red[0] / 8388608.0f;
    return;
  }
  int i = (blockIdx.x - 1) * 256 + threadIdx.x;
  float na = embed_avg[i] * 0.99f + 0.01f * dwsum[i];
  out_nea[i] = na;
  out_nemb[i] = na / csk[i >> 7];
}

extern "C" void kernel_launch(void* const* d_in, const int* in_sizes, int n_in,
                              void* d_out, int out_size, void* d_ws, size_t ws_size,
                              hipStream_t stream) {
  const float* x   = (const float*)d_in[0];
  const float* emb = (const float*)d_in[1];
  const float* cs  = (const float*)d_in[2];
  const float* ea  = (const float*)d_in[3];

  float* out      = (float*)d_out;
  float* out_q    = out;                      // [65536,128]
  float* out_loss = out + 8388608;            // scalar
  float* out_idx  = out + 8388609;            // [65536]
  float* out_nemb = out + 8454145;            // [1024,128]
  float* out_ncs  = out + 8585217;            // [1024]
  float* out_nea  = out + 8586241;            // [1024,128]

  float* W        = (float*)d_ws;
  float* e2s      = W;                              // [0,1024)
  double* en2d    = (double*)(W + 1024);            // [1024,3072)
  char*  bpack    = (char*)(W + 3072);              // [3072,134144) 512KB image
  float* dwsum    = W + 3072;                       // aliases bpack (dead after argmin)
  float* embT     = W + 134144;                     // [134144,265216) (dead after fb)
  unsigned* bcount = (unsigned*)(W + 134144);       // aliases embT lower (after fb)
  int*   order    = (int*)(W + 199680);             // aliases embT upper (after fb)
  float* partial  = W + 265216;                     // 1024
  unsigned* icounts = (unsigned*)(W + 266240);      // 1024
  unsigned* offsets = (unsigned*)(W + 267264);      // 1024
  float* csk      = W + 268288;                     // 1024
  int*   nflag    = (int*)(W + 269312);             // 1 (+pad)
  int*   flags    = (int*)(W + 269328);             // 65536
  int*   idx_arr  = (int*)(W + 334864);             // 65536

  bprep_k<<<64, 256, 0, stream>>>(emb, bpack, embT, e2s, en2d, nflag);
  argmin_k<<<1024, 128, 0, stream>>>(x, bpack, e2s, idx_arr, out_idx, nflag, flags);
  fb_k<<<1024, 256, 0, stream>>>(x, embT, en2d, nflag, flags, idx_arr, out_idx);
  histb_k<<<64, 256, 0, stream>>>(idx_arr, bcount);
  scan_k<<<1, 1024, 0, stream>>>(bcount, icounts, offsets, cs, out_ncs, csk);
  scatter_k<<<64, 256, 0, stream>>>(idx_arr, bcount, order);
  fgather_k<<<1024, 512, 0, stream>>>(x, emb, offsets, icounts, order, out_q, dwsum, partial);
  emb_k<<<513, 256, 0, stream>>>(ea, dwsum, csk, partial, out_nemb, out_nea, out_loss);
}

// Round 11
// 134.854 us; speedup vs baseline: 1.1048x; 1.1048x over previous
//
#include <hip/hip_runtime.h>

typedef __attribute__((ext_vector_type(8))) short short8;
typedef __attribute__((ext_vector_type(4))) float f32x4;

constexpr int NTOK = 65536;
constexpr int DIM  = 128;
constexpr int NK   = 1024;

__device__ __forceinline__ unsigned short f2bf(float f) {
  unsigned int u = __float_as_uint(f);
  unsigned int r = u + 0x7fffu + ((u >> 16) & 1u);
  return (unsigned short)(r >> 16);
}
__device__ __forceinline__ float bf2f(unsigned short h) {
  return __uint_as_float(((unsigned int)h) << 16);
}

// ---- prep: emb -> frag-major bf16 hi|lo image for direct reg loads ----
// frag addr = chunk*16384 + kk*4096 + hilo*2048 + n*1024 + lane*16
// (lane = lo4*16 + l15; code = chunk*32 + n*16 + l15; dims kk*32+lo4*8..+8)
// + embT + f64 |e|^2 + scaled-key e2s; zeroes nflag.
__global__ void bprep_k(const float* __restrict__ emb, char* __restrict__ bp,
                        float* __restrict__ embT, float* __restrict__ e2s,
                        double* __restrict__ en2d, int* __restrict__ nflag) {
  int i = blockIdx.x * 256 + threadIdx.x;   // 0..16383
  if (i == 0) *nflag = 0;
  int c = i >> 4;          // code
  int g = i & 15;          // dim group (8 dims)
  float4 v0 = *(const float4*)&emb[c * 128 + g * 8];
  float4 v1 = *(const float4*)&emb[c * 128 + g * 8 + 4];
  float vf[8] = {v0.x, v0.y, v0.z, v0.w, v1.x, v1.y, v1.z, v1.w};
  unsigned short hh[8], ll[8];
  double pacc = 0.0;
#pragma unroll
  for (int j = 0; j < 8; j++) {
    hh[j] = f2bf(vf[j]);
    ll[j] = f2bf(vf[j] - bf2f(hh[j]));
    embT[(g * 8 + j) * NK + c] = vf[j];
    pacc = fma((double)vf[j], (double)vf[j], pacc);
  }
  uint4 hv, lv;
  hv.x = (unsigned)hh[0] | ((unsigned)hh[1] << 16); hv.y = (unsigned)hh[2] | ((unsigned)hh[3] << 16);
  hv.z = (unsigned)hh[4] | ((unsigned)hh[5] << 16); hv.w = (unsigned)hh[6] | ((unsigned)hh[7] << 16);
  lv.x = (unsigned)ll[0] | ((unsigned)ll[1] << 16); lv.y = (unsigned)ll[2] | ((unsigned)ll[3] << 16);
  lv.z = (unsigned)ll[4] | ((unsigned)ll[5] << 16); lv.w = (unsigned)ll[6] | ((unsigned)ll[7] << 16);
  int chunk = c >> 5, n = (c >> 4) & 1, cl = c & 15;
  int kk = g >> 2, l4 = g & 3;
  char* cb = bp + chunk * 16384 + kk * 4096 + n * 1024 + (l4 * 16 + cl) * 16;
  *(uint4*)cb = hv;
  *(uint4*)(cb + 2048) = lv;
#pragma unroll
  for (int mask = 1; mask < 16; mask <<= 1) pacc += __shfl_xor(pacc, mask);
  if (g == 0) {
    en2d[c] = pacc;
    e2s[c] = (float)(pacc * 134217728.0 + 1073741824.0);  // e2*2^27 + 2^30
  }
}

// ---- main: MFMA bf16-split distance + u32-key argmin ----
// 1024 blocks x 128 thr (2 waves). NO LDS, NO barriers: B-frags streamed
// global(L2)->reg via rotating 4-slot kk-pipeline (depth-3 prefetch).
// Wave tile 32 rows (m=2) x 32 cols per chunk; 32 chunks (full K).
__global__ __launch_bounds__(128, 2)
void argmin_k(const float* __restrict__ x, const char* __restrict__ bp,
              const float* __restrict__ e2s, int* __restrict__ idx_arr,
              float* __restrict__ out_idx, int* __restrict__ nflag,
              int* __restrict__ flags) {
  const int t    = threadIdx.x;
  const int lane = t & 63;
  const int w    = t >> 6;              // 0..1
  const int l15  = lane & 15;
  const int lo4  = lane >> 4;
  const int rbase = blockIdx.x * 64;
  const int lb16 = lane * 16;

  short8 F[4][4];   // [slot][frag: 2*hilo + n]

#define LOADF(S, C, KK)                                                        \
  {                                                                            \
    const char* _b = bp + ((C) * 16384 + (KK) * 4096) + lb16;                  \
    F[S][0] = *(const short8*)_b;                                              \
    F[S][1] = *(const short8*)(_b + 1024);                                     \
    F[S][2] = *(const short8*)(_b + 2048);                                     \
    F[S][3] = *(const short8*)(_b + 3072);                                     \
  }

  // prolog: first 3 kk-slots of chunk 0 in flight before anything else
  LOADF(0, 0, 0)
  LOADF(1, 0, 1)
  LOADF(2, 0, 2)

  // A-frags (m=2): global -> regs with in-reg bf16 hi/lo split
  short8 ah[2][4], al[2][4];
#pragma unroll
  for (int m = 0; m < 2; m++)
#pragma unroll
    for (int kk = 0; kk < 4; kk++) {
      const float* xp = &x[(rbase + w * 32 + m * 16 + l15) * 128 + kk * 32 + lo4 * 8];
      float4 v0 = *(const float4*)xp;
      float4 v1 = *(const float4*)(xp + 4);
      float vf[8] = {v0.x, v0.y, v0.z, v0.w, v1.x, v1.y, v1.z, v1.w};
      unsigned short hh[8], ll[8];
#pragma unroll
      for (int j = 0; j < 8; j++) {
        hh[j] = f2bf(vf[j]);
        ll[j] = f2bf(vf[j] - bf2f(hh[j]));
      }
      unsigned hu[4] = {(unsigned)hh[0] | ((unsigned)hh[1] << 16), (unsigned)hh[2] | ((unsigned)hh[3] << 16),
                        (unsigned)hh[4] | ((unsigned)hh[5] << 16), (unsigned)hh[6] | ((unsigned)hh[7] << 16)};
      unsigned lu[4] = {(unsigned)ll[0] | ((unsigned)ll[1] << 16), (unsigned)ll[2] | ((unsigned)ll[3] << 16),
                        (unsigned)ll[4] | ((unsigned)ll[5] << 16), (unsigned)ll[6] | ((unsigned)ll[7] << 16)};
      ah[m][kk] = *(short8*)hu;
      al[m][kk] = *(short8*)lu;
    }

  unsigned bv[2][4], b2[2][4];
#pragma unroll
  for (int m = 0; m < 2; m++)
#pragma unroll
    for (int r = 0; r < 4; r++) { bv[m][r] = 0xFFFFFFFFu; b2[m][r] = 0xFFFFFFFFu; }

  for (int c = 0; c < 32; c++) {
    float e2a = e2s[c * 32 + l15];
    float e2b = e2s[c * 32 + 16 + l15];

    f32x4 acc[2][2];
#pragma unroll
    for (int m = 0; m < 2; m++)
#pragma unroll
      for (int n = 0; n < 2; n++) acc[m][n] = (f32x4)(0.0f);

    // kk=0: prefetch this chunk's kk=3 into slot 3; compute slot 0
    LOADF(3, c, 3)
    {
#pragma unroll
      for (int m = 0; m < 2; m++) {
        acc[m][0] = __builtin_amdgcn_mfma_f32_16x16x32_bf16(ah[m][0], F[0][0], acc[m][0], 0, 0, 0);
        acc[m][1] = __builtin_amdgcn_mfma_f32_16x16x32_bf16(ah[m][0], F[0][1], acc[m][1], 0, 0, 0);
        acc[m][0] = __builtin_amdgcn_mfma_f32_16x16x32_bf16(ah[m][0], F[0][2], acc[m][0], 0, 0, 0);
        acc[m][1] = __builtin_amdgcn_mfma_f32_16x16x32_bf16(ah[m][0], F[0][3], acc[m][1], 0, 0, 0);
        acc[m][0] = __builtin_amdgcn_mfma_f32_16x16x32_bf16(al[m][0], F[0][0], acc[m][0], 0, 0, 0);
        acc[m][1] = __builtin_amdgcn_mfma_f32_16x16x32_bf16(al[m][0], F[0][1], acc[m][1], 0, 0, 0);
      }
    }
    // kk=1: prefetch next chunk kk=0 into slot 0; compute slot 1
    if (c < 31) LOADF(0, c + 1, 0)
    {
#pragma unroll
      for (int m = 0; m < 2; m++) {
        acc[m][0] = __builtin_amdgcn_mfma_f32_16x16x32_bf16(ah[m][1], F[1][0], acc[m][0], 0, 0, 0);
        acc[m][1] = __builtin_amdgcn_mfma_f32_16x16x32_bf16(ah[m][1], F[1][1], acc[m][1], 0, 0, 0);
        acc[m][0] = __builtin_amdgcn_mfma_f32_16x16x32_bf16(ah[m][1], F[1][2], acc[m][0], 0, 0, 0);
        acc[m][1] = __builtin_amdgcn_mfma_f32_16x16x32_bf16(ah[m][1], F[1][3], acc[m][1], 0, 0, 0);
        acc[m][0] = __builtin_amdgcn_mfma_f32_16x16x32_bf16(al[m][1], F[1][0], acc[m][0], 0, 0, 0);
        acc[m][1] = __builtin_amdgcn_mfma_f32_16x16x32_bf16(al[m][1], F[1][1], acc[m][1], 0, 0, 0);
      }
    }
    // kk=2: prefetch next chunk kk=1 into slot 1; compute slot 2
    if (c < 31) LOADF(1, c + 1, 1)
    {
#pragma unroll
      for (int m = 0; m < 2; m++) {
        acc[m][0] = __builtin_amdgcn_mfma_f32_16x16x32_bf16(ah[m][2], F[2][0], acc[m][0], 0, 0, 0);
        acc[m][1] = __builtin_amdgcn_mfma_f32_16x16x32_bf16(ah[m][2], F[2][1], acc[m][1], 0, 0, 0);
        acc[m][0] = __builtin_amdgcn_mfma_f32_16x16x32_bf16(ah[m][2], F[2][2], acc[m][0], 0, 0, 0);
        acc[m][1] = __builtin_amdgcn_mfma_f32_16x16x32_bf16(ah[m][2], F[2][3], acc[m][1], 0, 0, 0);
        acc[m][0] = __builtin_amdgcn_mfma_f32_16x16x32_bf16(al[m][2], F[2][0], acc[m][0], 0, 0, 0);
        acc[m][1] = __builtin_amdgcn_mfma_f32_16x16x32_bf16(al[m][2], F[2][1], acc[m][1], 0, 0, 0);
      }
    }
    // kk=3: prefetch next chunk kk=2 into slot 2; compute slot 3
    if (c < 31) LOADF(2, c + 1, 2)
    {
#pragma unroll
      for (int m = 0; m < 2; m++) {
        acc[m][0] = __builtin_amdgcn_mfma_f32_16x16x32_bf16(ah[m][3], F[3][0], acc[m][0], 0, 0, 0);
        acc[m][1] = __builtin_amdgcn_mfma_f32_16x16x32_bf16(ah[m][3], F[3][1], acc[m][1], 0, 0, 0);
        acc[m][0] = __builtin_amdgcn_mfma_f32_16x16x32_bf16(ah[m][3], F[3][2], acc[m][0], 0, 0, 0);
        acc[m][1] = __builtin_amdgcn_mfma_f32_16x16x32_bf16(ah[m][3], F[3][3], acc[m][1], 0, 0, 0);
        acc[m][0] = __builtin_amdgcn_mfma_f32_16x16x32_bf16(al[m][3], F[3][0], acc[m][0], 0, 0, 0);
        acc[m][1] = __builtin_amdgcn_mfma_f32_16x16x32_bf16(al[m][3], F[3][1], acc[m][1], 0, 0, 0);
      }
    }

    // u32-key epilogue: key = (u32(e2s - 2^28*dot) & ~1023) | col
#pragma unroll
    for (int n = 0; n < 2; n++) {
      unsigned col = (unsigned)(c * 32 + n * 16 + l15);
      float e2v = n ? e2b : e2a;
#pragma unroll
      for (int m = 0; m < 2; m++)
#pragma unroll
        for (int r = 0; r < 4; r++) {
          float ks = fmaf(acc[m][n][r], -268435456.0f, e2v);
          unsigned key = ((unsigned)ks & 0xFFFFFC00u) | col;
          unsigned old = bv[m][r];
          bv[m][r] = min(old, key);
          b2[m][r] = min(b2[m][r], max(old, key));
        }
    }
  }
#undef LOADF

  // reduce over the 16 column-lanes (u32 min keeps tie-break = smaller col)
#pragma unroll
  for (int m = 0; m < 2; m++)
#pragma unroll
    for (int r = 0; r < 4; r++) {
      unsigned v = bv[m][r], v2 = b2[m][r];
      for (int mask = 1; mask < 16; mask <<= 1) {
        unsigned ov = __shfl_xor(v, mask);
        unsigned o2 = __shfl_xor(v2, mask);
        v2 = min(min(v2, o2), max(v, ov));
        v  = min(v, ov);
      }
      if (l15 == 0) {
        int row = rbase + w * 32 + m * 16 + lo4 * 4 + r;
        int ii = (int)(v & 1023u);
        idx_arr[row] = ii;
        out_idx[row] = (float)ii;
        if ((v2 >> 10) - (v >> 10) < 39u) {   // gap < 3e-4 in score units
          int p = atomicAdd(nflag, 1); flags[p] = row;
        }
      }
    }
}

// ---- exact f64 recompute for near-tie rows (coalesced via embT) ----
__global__ __launch_bounds__(256)
void fb_k(const float* __restrict__ x, const float* __restrict__ embT,
          const double* __restrict__ en2d, const int* __restrict__ nflag,
          const int* __restrict__ flags, int* __restrict__ idx_arr,
          float* __restrict__ out_idx) {
  int n = *nflag;
  __shared__ double xsh[DIM];
  __shared__ double sv[256];
  __shared__ int    si[256];
  int t = threadIdx.x;
  for (int f = blockIdx.x; f < n; f += gridDim.x) {
    int row = flags[f];
    __syncthreads();
    if (t < DIM) xsh[t] = (double)x[row * DIM + t];
    __syncthreads();
    double xe0 = 0.0, xe1 = 0.0, xe2 = 0.0, xe3 = 0.0;
#pragma unroll 4
    for (int d = 0; d < DIM; d++) {
      float4 v = *(const float4*)&embT[d * NK + t * 4];
      double xd = xsh[d];
      xe0 = fma((double)v.x, xd, xe0);
      xe1 = fma((double)v.y, xd, xe1);
      xe2 = fma((double)v.z, xd, xe2);
      xe3 = fma((double)v.w, xd, xe3);
    }
    double s0 = en2d[t * 4 + 0] - 2.0 * xe0;
    double s1 = en2d[t * 4 + 1] - 2.0 * xe1;
    double s2 = en2d[t * 4 + 2] - 2.0 * xe2;
    double s3 = en2d[t * 4 + 3] - 2.0 * xe3;
    double bvv = s0; int bii = t * 4;
    if (s1 < bvv) { bvv = s1; bii = t * 4 + 1; }
    if (s2 < bvv) { bvv = s2; bii = t * 4 + 2; }
    if (s3 < bvv) { bvv = s3; bii = t * 4 + 3; }
    sv[t] = bvv; si[t] = bii;
    __syncthreads();
    for (int sh = 128; sh > 0; sh >>= 1) {
      if (t < sh) {
        double ov = sv[t + sh]; int oi = si[t + sh];
        if (ov < sv[t] || (ov == sv[t] && oi < si[t])) { sv[t] = ov; si[t] = oi; }
      }
      __syncthreads();
    }
    if (t == 0) { idx_arr[row] = si[0]; out_idx[row] = (float)si[0]; }
  }
}

// ---- per-block histogram (LDS bins, plain stores) ----
__global__ void histb_k(const int* __restrict__ idx, unsigned* __restrict__ bcount) {
  __shared__ unsigned bins[NK];
  int t = threadIdx.x;
  for (int b = t; b < NK; b += 256) bins[b] = 0u;
  __syncthreads();
#pragma unroll
  for (int j = 0; j < 4; j++)
    atomicAdd(&bins[idx[blockIdx.x * 1024 + j * 256 + t]], 1u);
  __syncthreads();
  for (int b = t; b < NK; b += 256) bcount[blockIdx.x * NK + b] = bins[b];
}

// ---- totals + scan + per-block starts + ncs/csk ----
__global__ void scan_k(unsigned* __restrict__ bcount, unsigned* __restrict__ icounts,
                       unsigned* __restrict__ offsets, const float* __restrict__ cs,
                       float* __restrict__ out_ncs, float* __restrict__ csk) {
  __shared__ unsigned sc[NK];
  __shared__ float sf[NK];
  int t = threadIdx.x;
  unsigned tot = 0;
#pragma unroll 8
  for (int b = 0; b < 64; b++) tot += bcount[b * NK + t];
  icounts[t] = tot;
  sc[t] = tot;
  __syncthreads();
  for (int off = 1; off < NK; off <<= 1) {
    unsigned v = (t >= off) ? sc[t - off] : 0u;
    __syncthreads();
    sc[t] += v;
    __syncthreads();
  }
  unsigned excl = sc[t] - tot;
  offsets[t] = excl;
  unsigned run = excl;
#pragma unroll 8
  for (int b = 0; b < 64; b++) {
    unsigned c = bcount[b * NK + t];
    bcount[b * NK + t] = run;          // becomes per-block start
    run += c;
  }
  float c0 = cs[t];
  float ncs = c0 * 0.99f + 0.01f * (float)tot;
  out_ncs[t] = ncs;
  sf[t] = c0;
  __syncthreads();
  for (int s = 512; s > 0; s >>= 1) {
    if (t < s) sf[t] += sf[t + s];
    __syncthreads();
  }
  float n = 0.99f * sf[0] + 655.36f;   // sum(ncs) = 0.99*sum(cs) + 0.01*65536
  csk[t] = (ncs + 1e-5f) / (n + 1024.0f * 1e-5f) * n;
}

// ---- scatter row ids (LDS cursors; no global atomics) ----
__global__ void scatter_k(const int* __restrict__ idx, const unsigned* __restrict__ bstart,
                          int* __restrict__ order) {
  __shared__ unsigned cur[NK];
  int t = threadIdx.x;
  for (int b = t; b < NK; b += 256) cur[b] = bstart[blockIdx.x * NK + b];
  __syncthreads();
#pragma unroll
  for (int j = 0; j < 4; j++) {
    int r = blockIdx.x * 1024 + j * 256 + t;
    unsigned p = atomicAdd(&cur[idx[r]], 1u);
    order[p] = r;
  }
}

// ---- fused gather: out_q, loss partials, dw_embed sums (no atomics) ----
__global__ __launch_bounds__(512)
void fgather_k(const float* __restrict__ x, const float* __restrict__ emb,
               const unsigned* __restrict__ offsets, const unsigned* __restrict__ icounts,
               const int* __restrict__ order, float* __restrict__ out_q,
               float* __restrict__ dwsum, float* __restrict__ partial) {
  int k = blockIdx.x, t = threadIdx.x;
  int d = t & 127, h = t >> 7;   // h = 0..3
  float e = emb[k * DIM + d];
  unsigned s = offsets[k], cnt = icounts[k];
  float acc = 0.f, ls = 0.f;
  for (unsigned j = h; j < cnt; j += 4) {
    int row = order[s + j];
    float xv = x[row * DIM + d];
    out_q[row * DIM + d] = e;
    acc += xv;
    float dd = e - xv;
    ls += dd * dd;
  }
  __shared__ float sa[512], sl[512];
  sa[t] = acc; sl[t] = ls;
  __syncthreads();
  if (t < 128) dwsum[k * DIM + t] = sa[t] + sa[t + 128] + sa[t + 256] + sa[t + 384];
  for (int sh = 256; sh > 0; sh >>= 1) {
    if (t < sh) sl[t] += sl[t + sh];
    __syncthreads();
  }
  if (t == 0) partial[k] = sl[0];
}

// ---- embed_avg EMA + new embedding; block 0 reduces loss ----
__global__ void emb_k(const float* __restrict__ embed_avg, const float* __restrict__ dwsum,
                      const float* __restrict__ csk, const float* __restrict__ partial,
                      float* __restrict__ out_nemb, float* __restrict__ out_nea,
                      float* __restrict__ out_loss) {
  if (blockIdx.x == 0) {
    __shared__ float red[256];
    int t = threadIdx.x;
    red[t] = partial[t] + partial[t + 256] + partial[t + 512] + partial[t + 768];
    __syncthreads();
    for (int sh = 128; sh > 0; sh >>= 1) {
      if (t < sh) red[t] += red[t + sh];
      __syncthreads();
    }
    if (t == 0) out_loss[0] = 2.0f * red[0] / 8388608.0f;
    return;
  }
  int i = (blockIdx.x - 1) * 256 + threadIdx.x;
  float na = embed_avg[i] * 0.99f + 0.01f * dwsum[i];
  out_nea[i] = na;
  out_nemb[i] = na / csk[i >> 7];
}

extern "C" void kernel_launch(void* const* d_in, const int* in_sizes, int n_in,
                              void* d_out, int out_size, void* d_ws, size_t ws_size,
                              hipStream_t stream) {
  const float* x   = (const float*)d_in[0];
  const float* emb = (const float*)d_in[1];
  const float* cs  = (const float*)d_in[2];
  const float* ea  = (const float*)d_in[3];

  float* out      = (float*)d_out;
  float* out_q    = out;                      // [65536,128]
  float* out_loss = out + 8388608;            // scalar
  float* out_idx  = out + 8388609;            // [65536]
  float* out_nemb = out + 8454145;            // [1024,128]
  float* out_ncs  = out + 8585217;            // [1024]
  float* out_nea  = out + 8586241;            // [1024,128]

  float* W        = (float*)d_ws;
  float* e2s      = W;                              // [0,1024)
  double* en2d    = (double*)(W + 1024);            // [1024,3072)
  char*  bpack    = (char*)(W + 3072);              // [3072,134144) 512KB image
  float* dwsum    = W + 3072;                       // aliases bpack (dead after argmin)
  float* embT     = W + 134144;                     // [134144,265216) (dead after fb)
  unsigned* bcount = (unsigned*)(W + 134144);       // aliases embT lower (after fb)
  int*   order    = (int*)(W + 199680);             // aliases embT upper (after fb)
  float* partial  = W + 265216;                     // 1024
  unsigned* icounts = (unsigned*)(W + 266240);      // 1024
  unsigned* offsets = (unsigned*)(W + 267264);      // 1024
  float* csk      = W + 268288;                     // 1024
  int*   nflag    = (int*)(W + 269312);             // 1 (+pad)
  int*   flags    = (int*)(W + 269328);             // 65536
  int*   idx_arr  = (int*)(W + 334864);             // 65536

  bprep_k<<<64, 256, 0, stream>>>(emb, bpack, embT, e2s, en2d, nflag);
  argmin_k<<<1024, 128, 0, stream>>>(x, bpack, e2s, idx_arr, out_idx, nflag, flags);
  fb_k<<<1024, 256, 0, stream>>>(x, embT, en2d, nflag, flags, idx_arr, out_idx);
  histb_k<<<64, 256, 0, stream>>>(idx_arr, bcount);
  scan_k<<<1, 1024, 0, stream>>>(bcount, icounts, offsets, cs, out_ncs, csk);
  scatter_k<<<64, 256, 0, stream>>>(idx_arr, bcount, order);
  fgather_k<<<1024, 512, 0, stream>>>(x, emb, offsets, icounts, order, out_q, dwsum, partial);
  emb_k<<<513, 256, 0, stream>>>(ea, dwsum, csk, partial, out_nemb, out_nea, out_loss);
}